// Round 12
// baseline (15272.112 us; speedup 1.0000x reference)
//
#include <hip/hip_runtime.h>

typedef unsigned short u16;
typedef unsigned int   u32;
typedef unsigned long long u64;
typedef short s16x4 __attribute__((ext_vector_type(4)));
typedef short s16x8 __attribute__((ext_vector_type(8)));
typedef float f32x4 __attribute__((ext_vector_type(4)));
typedef u32   u32x4 __attribute__((ext_vector_type(4)));

#define GK 1024

__device__ inline u16 f2bf(float f) {
    u32 u = __builtin_bit_cast(u32, f);
    u += 0x7FFFu + ((u >> 16) & 1u);
    return (u16)(u >> 16);
}
__device__ inline u16 f2h(float f) {
    _Float16 h = (_Float16)f;
    return __builtin_bit_cast(u16, h);
}
__device__ inline float h2f(u16 u) {
    return (float)__builtin_bit_cast(_Float16, u);
}
__device__ inline float fast_sigmoid(float x) {
    return __builtin_amdgcn_rcpf(1.f + __expf(-x));
}
__device__ inline float fast_tanh(float x) {
    return 1.f - 2.f * __builtin_amdgcn_rcpf(1.f + __expf(2.f * x));
}
__device__ inline f32x4 mfma16(s16x8 a, s16x8 b, f32x4 c) {
    return __builtin_amdgcn_mfma_f32_16x16x32_bf16(a, b, c, 0, 0, 0);
}
__device__ inline s16x8 mk8(s16x4 lo, s16x4 hi) {
    return __builtin_shufflevector(lo, hi, 0, 1, 2, 3, 4, 5, 6, 7);
}
// 16B agent-scope (sc1) load; caller MUST HWAIT() before consuming results
__device__ inline u32x4 ald16(const u16* p) {
    u32x4 v;
    asm volatile("global_load_dwordx4 %0, %1, off sc1" : "=v"(v) : "v"(p));
    return v;
}
#define HWAIT() do { asm volatile("s_waitcnt vmcnt(0)" ::: "memory"); \
                     __builtin_amdgcn_sched_barrier(0); } while (0)

// ---------------- f32 -> bf16 convert (x) ----------------
__global__ void k_f2bf(const float* __restrict__ in, u16* __restrict__ out, int n) {
    int i = (blockIdx.x * 256 + threadIdx.x) * 4;
    if (i < n) {
        float4 v = *(const float4*)(in + i);
        ushort4 o;
        o.x = f2bf(v.x); o.y = f2bf(v.y); o.z = f2bf(v.z); o.w = f2bf(v.w);
        *(ushort4*)(out + i) = o;
    }
}

// ---------------- transpose + convert: out[c][r] = bf16(in[r][c]) ----------------
__global__ void k_transpose_bf(const float* __restrict__ in, u16* __restrict__ out,
                               int R, int C) {
    __shared__ float tile[32][33];
    int tid = threadIdx.x;
    int xs = (tid & 7) * 4;
    int y  = tid >> 3;
    int r0 = blockIdx.y * 32, c0 = blockIdx.x * 32;
    float4 v = *(const float4*)(in + (size_t)(r0 + y) * C + c0 + xs);
    tile[y][xs + 0] = v.x; tile[y][xs + 1] = v.y;
    tile[y][xs + 2] = v.z; tile[y][xs + 3] = v.w;
    __syncthreads();
    ushort4 o;
    o.x = f2bf(tile[xs + 0][y]); o.y = f2bf(tile[xs + 1][y]);
    o.z = f2bf(tile[xs + 2][y]); o.w = f2bf(tile[xs + 3][y]);
    *(ushort4*)(out + (size_t)(c0 + y) * R + r0 + xs) = o;
}

// ---------------- in-place frag-pack of a [cols][1024] bf16 matrix ----------------
// Per 64B chunk (32 elems): out u64 words = [w0,w4,w1,w5,w2,w6,w3,w7] so that a
// dwordx4 at +r16*8 elems is the MFMA frag (k = r16*4 + (j&3) + 16*(j>>2)).
__global__ void k_wpackip(u16* __restrict__ wm) {
    int idx = blockIdx.x * 256 + threadIdx.x;
    u64* p = (u64*)(wm + (size_t)idx * 32);
    u64 w0 = p[0], w1 = p[1], w2 = p[2], w3 = p[3];
    u64 w4 = p[4], w5 = p[5], w6 = p[6], w7 = p[7];
    p[0] = w0; p[1] = w4; p[2] = w1; p[3] = w5;
    p[4] = w2; p[5] = w6; p[6] = w3; p[7] = w7;
}

// ---------------- unpack permuted hseq1 -> plain [t*32+b][1024] ----------------
__global__ void k_unpack(const u16* __restrict__ in, u16* __restrict__ out) {
    int idx = blockIdx.x * 256 + threadIdx.x;
    int slot = idx >> 12;
    int c = idx & 4095;
    int q = c >> 7, b = (c >> 2) & 31, ri = c & 3;
    const u16* p = in + (size_t)(slot + 1) * 32768 + q * 1024 + b * 32 + ri * 8;
    u64 lo = *(const u64*)p;
    u64 hi = *(const u64*)(p + 4);
    u16* o = out + (size_t)(slot * 32 + b) * 1024 + q * 32 + ri * 4;
    *(u64*)o = lo;
    *(u64*)(o + 16) = hi;
}

// ---------------- bf16 GEMM (A plain [M][1024]) ----------------
// MODE 0: xproj: orow=(m&511)*32+(m>>9), fp16 gate-interleaved.
// MODE 1: heads: orow=(m&31)*512+(m>>5); n<256 softplus+ymin -> mu; n>=256 -> log_sigma.
template<int MODE>
__launch_bounds__(256, 2)
__global__ void k_gemm(const u16* __restrict__ A, const u16* __restrict__ BT,
                       const float* __restrict__ bias,
                       u16* __restrict__ Cb, float* __restrict__ Cf,
                       const float* __restrict__ b2, const float* __restrict__ ymin,
                       int gridN) {
    int bid = blockIdx.x;
    int m0 = (bid / gridN) * 128, n0 = (bid % gridN) * 128;
    __shared__ u16 As[128 * 40];
    __shared__ u16 Bs[128 * 40];
    int tid = threadIdx.x;
    int lane = tid & 63, w = tid >> 6;
    int wr = w >> 1, wc = w & 1;
    int rr = lane & 15, r16 = lane >> 4;
    f32x4 acc[4][4] = {};
    for (int kt = 0; kt < GK / 32; ++kt) {
        int k0 = kt * 32;
#pragma unroll
        for (int it = 0; it < 2; ++it) {
            int idx = it * 256 + tid;
            int row = idx >> 2, ch = idx & 3;
            *(u32x4*)(&As[row * 40 + ch * 8]) =
                *(const u32x4*)(A + (size_t)(m0 + row) * GK + k0 + ch * 8);
            *(u32x4*)(&Bs[row * 40 + ch * 8]) =
                *(const u32x4*)(BT + (size_t)(n0 + row) * GK + k0 + ch * 8);
        }
        __syncthreads();
        s16x8 af[4], bfr[4];
#pragma unroll
        for (int i = 0; i < 4; ++i) {
            int abase = (wr * 64 + i * 16 + rr) * 40 + r16 * 4;
            af[i] = mk8(*(const s16x4*)(&As[abase]), *(const s16x4*)(&As[abase + 16]));
            int bbase = (wc * 64 + i * 16 + rr) * 40 + r16 * 4;
            bfr[i] = mk8(*(const s16x4*)(&Bs[bbase]), *(const s16x4*)(&Bs[bbase + 16]));
        }
#pragma unroll
        for (int i = 0; i < 4; ++i)
#pragma unroll
            for (int j = 0; j < 4; ++j)
                acc[i][j] = mfma16(af[i], bfr[j], acc[i][j]);
        __syncthreads();
    }
#pragma unroll
    for (int i = 0; i < 4; ++i) {
#pragma unroll
        for (int j = 0; j < 4; ++j) {
#pragma unroll
            for (int r = 0; r < 4; ++r) {
                int m = m0 + wr * 64 + i * 16 + r16 * 4 + r;
                int n = n0 + wc * 64 + j * 16 + rr;
                float v = acc[i][j][r];
                if (MODE == 0) {
                    v += bias[n];
                    int orow = (m & 511) * 32 + (m >> 9);
                    int colx = ((n & 1023) << 2) | (n >> 10);
                    Cb[(size_t)orow * 4096 + colx] = f2h(v);
                } else {
                    int orow = (m & 31) * 512 + (m >> 5);
                    if (n < 256) {
                        v += bias[n];
                        float sp = fmaxf(v, 0.f) + log1pf(expf(-fabsf(v)));
                        Cf[(size_t)orow * 256 + n] = sp + ymin[n];
                    } else {
                        v += b2[n - 256];
                        Cf[4194304 + (size_t)orow * 256 + (n - 256)] = v;
                    }
                }
            }
        }
    }
}

// ---------------- LSTM epilogue helpers (r11-proven) ----------------
__device__ inline float lstm_core(f32x4 acc, float ai, float af, float ag, float ao,
                                  float& c, int lane) {
    float r0 = acc[0], r1 = acc[1], r2 = acc[2], r3 = acc[3];
    float x0 = __shfl_xor(r0, 1), x1 = __shfl_xor(r1, 1);
    float x2 = __shfl_xor(r2, 1), x3 = __shfl_xor(r3, 1);
    bool o1 = lane & 1;
    float s0 = o1 ? x1 : r0, s1 = o1 ? r1 : x0;
    float s2 = o1 ? x3 : r2, s3 = o1 ? r3 : x2;
    float y0 = __shfl_xor(s0, 2), y1 = __shfl_xor(s1, 2);
    float y2 = __shfl_xor(s2, 2), y3 = __shfl_xor(s3, 2);
    bool o2 = lane & 2;
    float gi = (o2 ? y2 : s0) + ai;
    float gf = (o2 ? y3 : s1) + af;
    float gg = (o2 ? s2 : y0) + ag;
    float go = (o2 ? s3 : y1) + ao;
    float I  = fast_sigmoid(gi);
    float Fg = fast_sigmoid(gf);
    float G  = fast_tanh(gg);
    float O  = fast_sigmoid(go);
    c = Fg * c + I * G;
    return O * fast_tanh(c);
}
__device__ inline void pack_store(float h, int lane, u16* dst) {
    u32 hq = (u32)f2bf(h);
    u32 o4 = (u32)__shfl_xor((int)hq, 4);
    u32 m32 = (lane & 4) ? ((o4 & 0xffffu) | (hq << 16))
                         : ((hq & 0xffffu) | (o4 << 16));
    u32 o8 = (u32)__shfl_xor((int)m32, 8);
    u64 m64 = (lane & 8) ? (((u64)o8) | ((u64)m32 << 32))
                         : (((u64)m32) | ((u64)o8 << 32));
    if ((lane & 12) == 0)
        __hip_atomic_store((u64*)dst, m64, __ATOMIC_RELAXED, __HIP_MEMORY_SCOPE_AGENT);
}

// ---------------- fused 2-layer persistent LSTM, 64 blocks, streamed packed weights ----
// 64 blocks x 512 threads (8 waves). Block owns units [blk*16, blk*16+16) of BOTH layers
// (4 col-tiles of 16 gate-cols each). Weights frag-packed in global (k_wpackip), streamed
// from L2 as plain dwordx4. h slot layout [q(32)][b(32)][32] frag-packed; h loads are
// single-batch sc1 dwordx4 (one vmcnt wait). Waves: grp A (0-3) = (mt,qh): L0 + L1x,
// all 4 ct, K-half qh; grp B (4-7) = L1h. Partials via LDS. Flag sync as r11.
__launch_bounds__(512, 1)
__global__ void k_fused(const u16* __restrict__ Wp0, const u16* __restrict__ Wpx,
                        const u16* __restrict__ Wp1, const u16* __restrict__ xproj,
                        const float* __restrict__ b1,
                        u16* __restrict__ hseq0, u16* __restrict__ hseq1,
                        u32* __restrict__ flags) {
    __shared__ f32x4 part[2][4][4][64];   // [mt][ct][src: A-L0, A-L1x, B-qh0, B-qh1][lane]
    int tid = threadIdx.x, blk = blockIdx.x;
    int lane = tid & 63, w = tid >> 6;
    int grp = w >> 2, wl = w & 3;
    int mt = wl >> 1, qh = wl & 1;
    int rr = lane & 15, r16 = lane >> 4;

    // weight frag base pointers per col-tile (packed layout: frag at +q*32 elems)
    const u16* wsB[4];   // grp A: Wp0 (L0);  grp B: Wp1 (L1h)
    const u16* wsX[4];   // grp A only: Wpx (L1x)
#pragma unroll
    for (int ct = 0; ct < 4; ++ct) {
        size_t cg = (size_t)((rr & 3) * 1024 + blk * 16 + ct * 4 + (rr >> 2));
        size_t off = cg * GK + qh * 512 + r16 * 8;
        wsB[ct] = (grp ? Wp1 : Wp0) + off;
        wsX[ct] = Wpx + off;
    }

    // epilogue identity (grp A): lane -> (batch b_, units ue[0], ue[1])
    int b_ = mt * 16 + (lane >> 4) * 4 + (lane & 3);
    int uu = (lane >> 2) & 3;
    int ue[2];
    ue[0] = blk * 16 + (qh * 2) * 4 + uu;
    ue[1] = ue[0] + 4;
    float b1r[2][4];
#pragma unroll
    for (int e = 0; e < 2; ++e)
#pragma unroll
        for (int g = 0; g < 4; ++g) b1r[e][g] = b1[g * 1024 + ue[e]];
    const u16* xpe0 = xproj + (size_t)b_ * 4096 + (size_t)ue[0] * 4;
    const u16* xpe1 = xproj + (size_t)b_ * 4096 + (size_t)ue[1] * 4;
    float c0[2] = {0.f, 0.f}, c1[2] = {0.f, 0.f};

    int qs = blk >> 1, ps = blk & 1;                       // store geometry
    const int cbase = qh * 16384 + mt * 512 + rr * 32 + r16 * 8;   // consumer base

    for (int r = 0; r <= 512; ++r) {
        // ---- wave 0 polls 64 flags >= r (sc1); barrier releases block ----
        if (w == 0) {
            const u32* fp = flags + lane;
            while (true) {
                u32 v;
                asm volatile("global_load_dword %0, %1, off sc1\n\ts_waitcnt vmcnt(0)"
                             : "=v"(v) : "v"(fp) : "memory");
                if (__all((int)(v >= (u32)r))) break;
                __builtin_amdgcn_s_sleep(1);
            }
        }
        __syncthreads();
        __builtin_amdgcn_sched_barrier(0);

        f32x4 acc0[4] = {}, acc1[4] = {};
        u64 xv0 = 0, xv1 = 0;
        if (grp == 0) {
            if (r < 512) {
                xv0 = *(const u64*)(xpe0 + (size_t)r * 131072);
                xv1 = *(const u64*)(xpe1 + (size_t)r * 131072);
            }
            const u16* hp = hseq0 + (size_t)r * 32768 + cbase;
            u32x4 hf[16];
#pragma unroll
            for (int jj = 0; jj < 16; ++jj) hf[jj] = ald16(hp + jj * 1024);
            HWAIT();
#pragma unroll
            for (int jj = 0; jj < 16; ++jj) {
                s16x8 a = __builtin_bit_cast(s16x8, hf[jj]);
#pragma unroll
                for (int ct = 0; ct < 4; ++ct) {
                    acc0[ct] = mfma16(a, *(const s16x8*)(wsB[ct] + jj * 32), acc0[ct]);
                    acc1[ct] = mfma16(a, *(const s16x8*)(wsX[ct] + jj * 32), acc1[ct]);
                }
            }
            int o0 = (1 - qh) * 2;
            part[mt][o0][0][lane]     = acc0[o0];
            part[mt][o0 + 1][0][lane] = acc0[o0 + 1];
            part[mt][o0][1][lane]     = acc1[o0];
            part[mt][o0 + 1][1][lane] = acc1[o0 + 1];
        } else {
            if (r > 0) {
                const u16* hp = hseq1 + (size_t)(r - 1) * 32768 + cbase;
                u32x4 hf[16];
#pragma unroll
                for (int jj = 0; jj < 16; ++jj) hf[jj] = ald16(hp + jj * 1024);
                HWAIT();
#pragma unroll
                for (int jj = 0; jj < 16; ++jj) {
                    s16x8 a = __builtin_bit_cast(s16x8, hf[jj]);
#pragma unroll
                    for (int ct = 0; ct < 4; ++ct)
                        acc0[ct] = mfma16(a, *(const s16x8*)(wsB[ct] + jj * 32), acc0[ct]);
                }
            }
#pragma unroll
            for (int ct = 0; ct < 4; ++ct)
                part[mt][ct][2 + qh][lane] = acc0[ct];
        }
        __syncthreads();   // partials published

        if (grp == 0) {
#pragma unroll
            for (int e = 0; e < 2; ++e) {
                int ct = qh * 2 + e;
                u64 xv = e ? xv1 : xv0;
                if (r < 512) {
                    f32x4 acc = acc0[ct] + part[mt][ct][0][lane];
                    float h = lstm_core(acc, h2f((u16)xv), h2f((u16)(xv >> 16)),
                                        h2f((u16)(xv >> 32)), h2f((u16)(xv >> 48)),
                                        c0[e], lane);
                    pack_store(h, lane, hseq0 + (size_t)(r + 1) * 32768
                               + qs * 1024 + b_ * 32 + ct * 8 + ps * 4);
                }
                if (r > 0) {
                    f32x4 acc = acc1[ct] + part[mt][ct][1][lane]
                              + part[mt][ct][2][lane] + part[mt][ct][3][lane];
                    float h = lstm_core(acc, b1r[e][0], b1r[e][1], b1r[e][2], b1r[e][3],
                                        c1[e], lane);
                    pack_store(h, lane, hseq1 + (size_t)r * 32768
                               + qs * 1024 + b_ * 32 + ct * 8 + ps * 4);
                }
            }
        }
        __syncthreads();   // drains sc1 stores (vmcnt) before flag post
        if (tid == 0)
            __hip_atomic_store(&flags[blk], (u32)(r + 1), __ATOMIC_RELAXED,
                               __HIP_MEMORY_SCOPE_AGENT);
    }
}

extern "C" void kernel_launch(void* const* d_in, const int* in_sizes, int n_in,
                              void* d_out, int out_size, void* d_ws, size_t ws_size,
                              hipStream_t stream) {
    const float* x   = (const float*)d_in[0];
    const float* Wx  = (const float*)d_in[1];
    const float* Wh  = (const float*)d_in[2];
    const float* b   = (const float*)d_in[3];
    const float* Wmu = (const float*)d_in[4];
    const float* bmu = (const float*)d_in[5];
    const float* Wls = (const float*)d_in[6];
    const float* bls = (const float*)d_in[7];
    const float* ym  = (const float*)d_in[8];
    float* out = (float*)d_out;

    // workspace (236,061,184 B) -- identical map to r11:
    char* ws = (char*)d_ws;
    u16* hseq0 = (u16*)(ws);                  // 33,619,968 (aliases xbf; sc1-read only)
    u16* xbf   = (u16*)(ws);
    u16* hseq1 = (u16*)(ws + 33619968);       // 33,619,968
    u16* wxT   = (u16*)(ws + 67239936);       // 16,777,216 [2][4096][1024]
    u16* whT   = (u16*)(ws + 84017152);       // 16,777,216 (frag-packed in place)
    u16* whdT  = (u16*)(ws + 100794368);      //  1,048,576
    u16* xproj = (u16*)(ws + 101842944);      // 134,217,728 (h1lin alias after k_fused)
    u16* h1lin = xproj;
    u32* flags = (u32*)(ws + 236060672);      // 512

    // prep
    k_f2bf<<<16384, 256, 0, stream>>>(x, xbf, 16777216);
    dim3 tg(128, 32);
    k_transpose_bf<<<tg, 256, 0, stream>>>(Wx,           wxT,           1024, 4096);
    k_transpose_bf<<<tg, 256, 0, stream>>>(Wx + 4194304, wxT + 4194304, 1024, 4096);
    k_transpose_bf<<<tg, 256, 0, stream>>>(Wh,           whT,           1024, 4096);
    k_transpose_bf<<<tg, 256, 0, stream>>>(Wh + 4194304, whT + 4194304, 1024, 4096);
    dim3 hg(8, 32);
    k_transpose_bf<<<hg, 256, 0, stream>>>(Wmu, whdT,          1024, 256);
    k_transpose_bf<<<hg, 256, 0, stream>>>(Wls, whdT + 262144, 1024, 256);

    // layer-0 x-projection (uses UNPACKED wxT[0])
    k_gemm<0><<<4096, 256, 0, stream>>>(xbf, wxT, b, xproj, nullptr, nullptr, nullptr, 32);

    // frag-pack weights in place: whT (both layers) and wxT layer 1
    k_wpackip<<<1024, 256, 0, stream>>>(whT);
    k_wpackip<<<512, 256, 0, stream>>>(wxT + 4194304);

    // zero initial h slots + flags (xbf dead now; hseq0 aliases it)
    hipMemsetAsync(hseq0, 0, 65536, stream);
    hipMemsetAsync(hseq1, 0, 65536, stream);
    hipMemsetAsync(flags, 0, 512, stream);

    // fused 2-layer recurrence: 64 blocks, streamed packed weights, 16B sc1 h loads
    k_fused<<<64, 512, 0, stream>>>(whT, wxT + 4194304, whT + 4194304, xproj,
                                    b + 4096, hseq0, hseq1, flags);

    // unpack hseq1 -> plain rows, then heads
    k_unpack<<<8192, 256, 0, stream>>>(hseq1, h1lin);
    k_gemm<1><<<512, 256, 0, stream>>>(h1lin, whdT, bmu, nullptr, out, bls, ym, 4);
}

// Round 14
// 10472.256 us; speedup vs baseline: 1.4583x; 1.4583x over previous
//
#include <hip/hip_runtime.h>

typedef unsigned short u16;
typedef unsigned int   u32;
typedef unsigned long long u64;
typedef short s16x4 __attribute__((ext_vector_type(4)));
typedef short s16x8 __attribute__((ext_vector_type(8)));
typedef float f32x4 __attribute__((ext_vector_type(4)));
typedef u32   u32x4 __attribute__((ext_vector_type(4)));

#define GK 1024

__device__ inline u16 f2bf(float f) {
    u32 u = __builtin_bit_cast(u32, f);
    u += 0x7FFFu + ((u >> 16) & 1u);
    return (u16)(u >> 16);
}
__device__ inline u16 f2h(float f) {
    _Float16 h = (_Float16)f;
    return __builtin_bit_cast(u16, h);
}
__device__ inline float h2f(u16 u) {
    return (float)__builtin_bit_cast(_Float16, u);
}
__device__ inline float fast_sigmoid(float x) {
    return __builtin_amdgcn_rcpf(1.f + __expf(-x));
}
__device__ inline float fast_tanh(float x) {
    return 1.f - 2.f * __builtin_amdgcn_rcpf(1.f + __expf(2.f * x));
}
__device__ inline f32x4 mfma16(s16x8 a, s16x8 b, f32x4 c) {
    return __builtin_amdgcn_mfma_f32_16x16x32_bf16(a, b, c, 0, 0, 0);
}
__device__ inline s16x8 mk8(s16x4 lo, s16x4 hi) {
    return __builtin_shufflevector(lo, hi, 0, 1, 2, 3, 4, 5, 6, 7);
}
// 16B agent-scope (sc1) load; caller must HWAIT before consuming
__device__ inline u32x4 ald16(const u16* p) {
    u32x4 v;
    asm volatile("global_load_dwordx4 %0, %1, off sc1" : "=v"(v) : "v"(p));
    return v;
}
__device__ inline u32 aldf(const u32* p) {
    return __hip_atomic_load(p, __ATOMIC_RELAXED, __HIP_MEMORY_SCOPE_AGENT);
}
#define HWAIT() do { asm volatile("s_waitcnt vmcnt(0)" ::: "memory"); \
                     __builtin_amdgcn_sched_barrier(0); } while (0)

// ---------------- f32 -> bf16 convert (x) ----------------
__global__ void k_f2bf(const float* __restrict__ in, u16* __restrict__ out, int n) {
    int i = (blockIdx.x * 256 + threadIdx.x) * 4;
    if (i < n) {
        float4 v = *(const float4*)(in + i);
        ushort4 o;
        o.x = f2bf(v.x); o.y = f2bf(v.y); o.z = f2bf(v.z); o.w = f2bf(v.w);
        *(ushort4*)(out + i) = o;
    }
}

// ---------------- transpose + convert: out[c][r] = bf16(in[r][c]) ----------------
__global__ void k_transpose_bf(const float* __restrict__ in, u16* __restrict__ out,
                               int R, int C) {
    __shared__ float tile[32][33];
    int tid = threadIdx.x;
    int xs = (tid & 7) * 4;
    int y  = tid >> 3;
    int r0 = blockIdx.y * 32, c0 = blockIdx.x * 32;
    float4 v = *(const float4*)(in + (size_t)(r0 + y) * C + c0 + xs);
    tile[y][xs + 0] = v.x; tile[y][xs + 1] = v.y;
    tile[y][xs + 2] = v.z; tile[y][xs + 3] = v.w;
    __syncthreads();
    ushort4 o;
    o.x = f2bf(tile[xs + 0][y]); o.y = f2bf(tile[xs + 1][y]);
    o.z = f2bf(tile[xs + 2][y]); o.w = f2bf(tile[xs + 3][y]);
    *(ushort4*)(out + (size_t)(c0 + y) * R + r0 + xs) = o;
}

// ---------------- unpack permuted hseq1 -> plain [t*32+b][1024] (r12-proven) ----------
__global__ void k_unpack(const u16* __restrict__ in, u16* __restrict__ out) {
    int idx = blockIdx.x * 256 + threadIdx.x;
    int slot = idx >> 12;
    int c = idx & 4095;
    int q = c >> 7, b = (c >> 2) & 31, ri = c & 3;
    const u16* p = in + (size_t)(slot + 1) * 32768 + q * 1024 + b * 32 + ri * 8;
    u64 lo = *(const u64*)p;
    u64 hi = *(const u64*)(p + 4);
    u16* o = out + (size_t)(slot * 32 + b) * 1024 + q * 32 + ri * 4;
    *(u64*)o = lo;
    *(u64*)(o + 16) = hi;
}

// ---------------- bf16 GEMM (A plain [M][1024]) ----------------
// MODE 0: xproj: orow=(m&511)*32+(m>>9), fp16 gate-interleaved.
// MODE 1: heads: orow=(m&31)*512+(m>>5); n<256 softplus+ymin -> mu; n>=256 -> log_sigma.
template<int MODE>
__launch_bounds__(256, 2)
__global__ void k_gemm(const u16* __restrict__ A, const u16* __restrict__ BT,
                       const float* __restrict__ bias,
                       u16* __restrict__ Cb, float* __restrict__ Cf,
                       const float* __restrict__ b2, const float* __restrict__ ymin,
                       int gridN) {
    int bid = blockIdx.x;
    int m0 = (bid / gridN) * 128, n0 = (bid % gridN) * 128;
    __shared__ u16 As[128 * 40];
    __shared__ u16 Bs[128 * 40];
    int tid = threadIdx.x;
    int lane = tid & 63, w = tid >> 6;
    int wr = w >> 1, wc = w & 1;
    int rr = lane & 15, r16 = lane >> 4;
    f32x4 acc[4][4] = {};
    for (int kt = 0; kt < GK / 32; ++kt) {
        int k0 = kt * 32;
#pragma unroll
        for (int it = 0; it < 2; ++it) {
            int idx = it * 256 + tid;
            int row = idx >> 2, ch = idx & 3;
            *(u32x4*)(&As[row * 40 + ch * 8]) =
                *(const u32x4*)(A + (size_t)(m0 + row) * GK + k0 + ch * 8);
            *(u32x4*)(&Bs[row * 40 + ch * 8]) =
                *(const u32x4*)(BT + (size_t)(n0 + row) * GK + k0 + ch * 8);
        }
        __syncthreads();
        s16x8 af[4], bfr[4];
#pragma unroll
        for (int i = 0; i < 4; ++i) {
            int abase = (wr * 64 + i * 16 + rr) * 40 + r16 * 4;
            af[i] = mk8(*(const s16x4*)(&As[abase]), *(const s16x4*)(&As[abase + 16]));
            int bbase = (wc * 64 + i * 16 + rr) * 40 + r16 * 4;
            bfr[i] = mk8(*(const s16x4*)(&Bs[bbase]), *(const s16x4*)(&Bs[bbase + 16]));
        }
#pragma unroll
        for (int i = 0; i < 4; ++i)
#pragma unroll
            for (int j = 0; j < 4; ++j)
                acc[i][j] = mfma16(af[i], bfr[j], acc[i][j]);
        __syncthreads();
    }
#pragma unroll
    for (int i = 0; i < 4; ++i) {
#pragma unroll
        for (int j = 0; j < 4; ++j) {
#pragma unroll
            for (int r = 0; r < 4; ++r) {
                int m = m0 + wr * 64 + i * 16 + r16 * 4 + r;
                int n = n0 + wc * 64 + j * 16 + rr;
                float v = acc[i][j][r];
                if (MODE == 0) {
                    v += bias[n];
                    int orow = (m & 511) * 32 + (m >> 9);
                    int colx = ((n & 1023) << 2) | (n >> 10);
                    Cb[(size_t)orow * 4096 + colx] = f2h(v);
                } else {
                    int orow = (m & 31) * 512 + (m >> 5);
                    if (n < 256) {
                        v += bias[n];
                        float sp = fmaxf(v, 0.f) + log1pf(expf(-fabsf(v)));
                        Cf[(size_t)orow * 256 + n] = sp + ymin[n];
                    } else {
                        v += b2[n - 256];
                        Cf[4194304 + (size_t)orow * 256 + (n - 256)] = v;
                    }
                }
            }
        }
    }
}

// ---------------- LSTM epilogue helpers (proven r11/r12) ----------------
__device__ inline float lstm_core(f32x4 acc, float ai, float af, float ag, float ao,
                                  float& c, int lane) {
    float r0 = acc[0], r1 = acc[1], r2 = acc[2], r3 = acc[3];
    float x0 = __shfl_xor(r0, 1), x1 = __shfl_xor(r1, 1);
    float x2 = __shfl_xor(r2, 1), x3 = __shfl_xor(r3, 1);
    bool o1 = lane & 1;
    float s0 = o1 ? x1 : r0, s1 = o1 ? r1 : x0;
    float s2 = o1 ? x3 : r2, s3 = o1 ? r3 : x2;
    float y0 = __shfl_xor(s0, 2), y1 = __shfl_xor(s1, 2);
    float y2 = __shfl_xor(s2, 2), y3 = __shfl_xor(s3, 2);
    bool o2 = lane & 2;
    float gi = (o2 ? y2 : s0) + ai;
    float gf = (o2 ? y3 : s1) + af;
    float gg = (o2 ? s2 : y0) + ag;
    float go = (o2 ? s3 : y1) + ao;
    float I  = fast_sigmoid(gi);
    float Fg = fast_sigmoid(gf);
    float G  = fast_tanh(gg);
    float O  = fast_sigmoid(go);
    c = Fg * c + I * G;
    return O * fast_tanh(c);
}
__device__ inline void pack_store(float h, int lane, u16* dst) {
    u32 hq = (u32)f2bf(h);
    u32 o4 = (u32)__shfl_xor((int)hq, 4);
    u32 m32 = (lane & 4) ? ((o4 & 0xffffu) | (hq << 16))
                         : ((hq & 0xffffu) | (o4 << 16));
    u32 o8 = (u32)__shfl_xor((int)m32, 8);
    u64 m64 = (lane & 8) ? (((u64)o8) | ((u64)m32 << 32))
                         : (((u64)m32) | ((u64)o8 << 32));
    if ((lane & 12) == 0)
        __hip_atomic_store((u64*)dst, m64, __ATOMIC_RELAXED, __HIP_MEMORY_SCOPE_AGENT);
}
__device__ inline int e0_of(int base) {   // elem offset of unit-group base (verified)
    return ((base & 15) >> 2) * 8 + ((base >> 4) & 1) * 4;
}

// ---------------- fused 2-layer persistent LSTM, DECOUPLED wave groups ----------------
// 128 blocks x 256 threads (4 waves). Block owns units [blk*8,+8) of both layers.
// h slot layout [q(32)][b(32)][32] frag-packed. Waves 0,1 (mt=w): pure L0 loop.
// Waves 2,3 (mt=w-2): all of L1 (L1h from LDS Wh1; L1x from streamed Wx1), one round
// behind. One flag per (group, block); the two mt-waves rendezvous via LDS done[]
// (drain stores -> post done -> wave mt=0 lane0 spins partner -> posts agent flag).
// No __syncthreads in the loops. Deadlock-free: A self-chains, B trails A; guards
// fail fast to wrong-answer instead of hang.
__launch_bounds__(256, 1)
__global__ void k_fused(const u16* __restrict__ Wh0T, const u16* __restrict__ Wx1T,
                        const u16* __restrict__ Wh1T, const u16* __restrict__ xproj,
                        const float* __restrict__ b1,
                        u16* __restrict__ hseq0, u16* __restrict__ hseq1,
                        u32* __restrict__ flagA, u32* __restrict__ flagB) {
    __shared__ u16 wlds[2][32][2][64][8];   // [layer][q][ct][lane][8] B-frags, 128 KB
    __shared__ u32 done[4];                 // [0]=A-mt0 [1]=A-mt1 [2]=B-mt0 [3]=B-mt1
    int tid = threadIdx.x, blk = blockIdx.x;
    int lane = tid & 63, w = tid >> 6;
    int rr = lane & 15, r16 = lane >> 4;

    if (tid == 0) { done[0] = done[1] = done[2] = done[3] = 0; }
    // ---- one-time weight preload: wave w -> layer w>>1, col-tile w&1 ----
    {
        int g = w >> 1, ct = w & 1;
        int cg = (rr & 3) * 1024 + blk * 8 + ct * 4 + (rr >> 2);
        const u16* src = (g ? Wh1T : Wh0T) + (size_t)cg * GK + r16 * 4;
#pragma unroll
        for (int q = 0; q < 32; ++q)
            *(s16x8*)(&wlds[g][q][ct][lane][0]) =
                mk8(*(const s16x4*)(src + q * 32), *(const s16x4*)(src + q * 32 + 16));
    }
    __syncthreads();   // the ONLY barrier

    int mt = w & 1;
    int b_ = mt * 16 + (lane >> 4) * 4 + (lane & 3);
    int uu = (lane >> 2) & 3;
    int sblk = blk & 3, q_blk = blk >> 2;
    int E0_0 = e0_of(sblk * 8);
    int E0_1 = e0_of(sblk * 8 + 4);
    const int cb = mt * 512 + rr * 32 + r16 * 8;

    if (w < 2) {
        // ================= GROUP A: layer-0 only =================
        const u16* xpe0 = xproj + (size_t)b_ * 4096 + (size_t)(blk * 8 + uu) * 4;
        const u16* xpe1 = xpe0 + 16;   // +4 units
        const u16* wq0 = &wlds[0][0][0][lane][0];   // q stride 2048 B
        const u16* wq1 = &wlds[0][0][1][lane][0];
        float cc0 = 0.f, cc1 = 0.f;
        for (int r = 0; r < 512; ++r) {
            int guard = 0;
            while (true) {
                u32 v0 = aldf(flagA + lane);
                u32 v1 = aldf(flagA + 64 + lane);
                if (__all((v0 >= (u32)r) & (v1 >= (u32)r))) break;
                if (++guard > (1 << 17)) break;
                __builtin_amdgcn_s_sleep(1);
            }
            __builtin_amdgcn_sched_barrier(0);

            u64 xv0 = *(const u64*)(xpe0 + (size_t)r * 131072);
            u64 xv1 = *(const u64*)(xpe1 + (size_t)r * 131072);
            const u16* hp = hseq0 + (size_t)r * 32768 + cb;
            u32x4 hf[32];
#pragma unroll
            for (int jj = 0; jj < 32; ++jj) hf[jj] = ald16(hp + jj * 1024);
            HWAIT();
            f32x4 a0 = {}, a1 = {};
#pragma unroll
            for (int jj = 0; jj < 32; ++jj) {
                s16x8 a = __builtin_bit_cast(s16x8, hf[jj]);
                a0 = mfma16(a, *(const s16x8*)(wq0 + (size_t)jj * 1024), a0);
                a1 = mfma16(a, *(const s16x8*)(wq1 + (size_t)jj * 1024), a1);
            }
            float h0v = lstm_core(a0, h2f((u16)xv0), h2f((u16)(xv0 >> 16)),
                                  h2f((u16)(xv0 >> 32)), h2f((u16)(xv0 >> 48)), cc0, lane);
            float h1v = lstm_core(a1, h2f((u16)xv1), h2f((u16)(xv1 >> 16)),
                                  h2f((u16)(xv1 >> 32)), h2f((u16)(xv1 >> 48)), cc1, lane);
            u16* dst = hseq0 + (size_t)(r + 1) * 32768 + q_blk * 1024 + b_ * 32;
            pack_store(h0v, lane, dst + E0_0);
            pack_store(h1v, lane, dst + E0_1);
            asm volatile("s_waitcnt vmcnt(0)" ::: "memory");
            __hip_atomic_store(&done[mt], (u32)(r + 1), __ATOMIC_RELAXED,
                               __HIP_MEMORY_SCOPE_WORKGROUP);
            if (mt == 0 && lane == 0) {
                int g2 = 0;
                while (__hip_atomic_load(&done[1], __ATOMIC_RELAXED,
                                         __HIP_MEMORY_SCOPE_WORKGROUP) < (u32)(r + 1)
                       && ++g2 < (1 << 20))
                    __builtin_amdgcn_s_sleep(1);
                __hip_atomic_store(&flagA[blk], (u32)(r + 1), __ATOMIC_RELAXED,
                                   __HIP_MEMORY_SCOPE_AGENT);
            }
        }
    } else {
        // ================= GROUP B: layer-1 entirely =================
        const u16* wq0 = &wlds[1][0][0][lane][0];
        const u16* wq1 = &wlds[1][0][1][lane][0];
        u64 wx0_u = (u64)(uintptr_t)(Wx1T +
            (size_t)((rr & 3) * 1024 + blk * 8 + (rr >> 2)) * GK + r16 * 4);
        u64 wx1_u = wx0_u + 4 * GK * 2;   // +4 cols (bytes)
        float b1r[2][4];
#pragma unroll
        for (int e = 0; e < 2; ++e)
#pragma unroll
            for (int g = 0; g < 4; ++g)
                b1r[e][g] = b1[g * 1024 + blk * 8 + e * 4 + uu];
        float cc0 = 0.f, cc1 = 0.f;
        for (int r = 1; r <= 512; ++r) {
            int guard = 0;
            while (true) {
                u32 a0f = aldf(flagA + lane);
                u32 a1f = aldf(flagA + 64 + lane);
                u32 b0f = aldf(flagB + lane);
                u32 b1f = aldf(flagB + 64 + lane);
                if (__all((a0f >= (u32)r) & (a1f >= (u32)r) &
                          (b0f >= (u32)(r - 1)) & (b1f >= (u32)(r - 1)))) break;
                if (++guard > (1 << 17)) break;
                __builtin_amdgcn_s_sleep(1);
            }
            __builtin_amdgcn_sched_barrier(0);

            // batch 1: h1[r-1] -> L1h (Wh1 in LDS)
            const u16* hp1 = hseq1 + (size_t)(r - 1) * 32768 + cb;
            u32x4 hf[32];
#pragma unroll
            for (int jj = 0; jj < 32; ++jj) hf[jj] = ald16(hp1 + jj * 1024);
            HWAIT();
            f32x4 hA0 = {}, hA1 = {};
#pragma unroll
            for (int jj = 0; jj < 32; ++jj) {
                s16x8 a = __builtin_bit_cast(s16x8, hf[jj]);
                hA0 = mfma16(a, *(const s16x8*)(wq0 + (size_t)jj * 1024), hA0);
                hA1 = mfma16(a, *(const s16x8*)(wq1 + (size_t)jj * 1024), hA1);
            }
            // batch 2 (reuses hf): h0[r] -> L1x (Wx1 streamed from L2)
            const u16* hp0 = hseq0 + (size_t)r * 32768 + cb;
#pragma unroll
            for (int jj = 0; jj < 32; ++jj) hf[jj] = ald16(hp0 + jj * 1024);
            HWAIT();
            asm volatile("" : "+v"(wx0_u), "+v"(wx1_u));   // defeat LICM of Wx1 stream
            const u16* wx0 = (const u16*)(uintptr_t)wx0_u;
            const u16* wx1 = (const u16*)(uintptr_t)wx1_u;
            f32x4 xA0 = {}, xA1 = {};
#pragma unroll
            for (int jj = 0; jj < 32; ++jj) {
                s16x8 a = __builtin_bit_cast(s16x8, hf[jj]);
                s16x8 bx0 = mk8(*(const s16x4*)(wx0 + jj * 32),
                                *(const s16x4*)(wx0 + jj * 32 + 16));
                s16x8 bx1 = mk8(*(const s16x4*)(wx1 + jj * 32),
                                *(const s16x4*)(wx1 + jj * 32 + 16));
                xA0 = mfma16(a, bx0, xA0);
                xA1 = mfma16(a, bx1, xA1);
            }
            float h0v = lstm_core(hA0 + xA0, b1r[0][0], b1r[0][1], b1r[0][2], b1r[0][3],
                                  cc0, lane);
            float h1v = lstm_core(hA1 + xA1, b1r[1][0], b1r[1][1], b1r[1][2], b1r[1][3],
                                  cc1, lane);
            u16* dst = hseq1 + (size_t)r * 32768 + q_blk * 1024 + b_ * 32;
            pack_store(h0v, lane, dst + E0_0);
            pack_store(h1v, lane, dst + E0_1);
            asm volatile("s_waitcnt vmcnt(0)" ::: "memory");
            __hip_atomic_store(&done[2 + mt], (u32)r, __ATOMIC_RELAXED,
                               __HIP_MEMORY_SCOPE_WORKGROUP);
            if (mt == 0 && lane == 0) {
                int g2 = 0;
                while (__hip_atomic_load(&done[3], __ATOMIC_RELAXED,
                                         __HIP_MEMORY_SCOPE_WORKGROUP) < (u32)r
                       && ++g2 < (1 << 20))
                    __builtin_amdgcn_s_sleep(1);
                __hip_atomic_store(&flagB[blk], (u32)r, __ATOMIC_RELAXED,
                                   __HIP_MEMORY_SCOPE_AGENT);
            }
        }
    }
}

extern "C" void kernel_launch(void* const* d_in, const int* in_sizes, int n_in,
                              void* d_out, int out_size, void* d_ws, size_t ws_size,
                              hipStream_t stream) {
    const float* x   = (const float*)d_in[0];
    const float* Wx  = (const float*)d_in[1];
    const float* Wh  = (const float*)d_in[2];
    const float* b   = (const float*)d_in[3];
    const float* Wmu = (const float*)d_in[4];
    const float* bmu = (const float*)d_in[5];
    const float* Wls = (const float*)d_in[6];
    const float* bls = (const float*)d_in[7];
    const float* ym  = (const float*)d_in[8];
    float* out = (float*)d_out;

    // workspace (236,061,696 B -- r8-proven boundary):
    char* ws = (char*)d_ws;
    u16* hseq0 = (u16*)(ws);                  // 33,619,968 (aliases xbf; sc1-read only)
    u16* xbf   = (u16*)(ws);
    u16* hseq1 = (u16*)(ws + 33619968);       // 33,619,968
    u16* wxT   = (u16*)(ws + 67239936);       // 16,777,216 [2][4096][1024]
    u16* whT   = (u16*)(ws + 84017152);       // 16,777,216
    u16* whdT  = (u16*)(ws + 100794368);      //  1,048,576
    u16* xproj = (u16*)(ws + 101842944);      // 134,217,728 (h1lin alias after k_fused)
    u16* h1lin = xproj;
    u32* flagA = (u32*)(ws + 236060672);      // 512 B (128 u32)
    u32* flagB = (u32*)(ws + 236061184);      // 512 B (128 u32)

    // prep
    k_f2bf<<<16384, 256, 0, stream>>>(x, xbf, 16777216);
    dim3 tg(128, 32);
    k_transpose_bf<<<tg, 256, 0, stream>>>(Wx,           wxT,           1024, 4096);
    k_transpose_bf<<<tg, 256, 0, stream>>>(Wx + 4194304, wxT + 4194304, 1024, 4096);
    k_transpose_bf<<<tg, 256, 0, stream>>>(Wh,           whT,           1024, 4096);
    k_transpose_bf<<<tg, 256, 0, stream>>>(Wh + 4194304, whT + 4194304, 1024, 4096);
    dim3 hg(8, 32);
    k_transpose_bf<<<hg, 256, 0, stream>>>(Wmu, whdT,          1024, 256);
    k_transpose_bf<<<hg, 256, 0, stream>>>(Wls, whdT + 262144, 1024, 256);

    // layer-0 x-projection
    k_gemm<0><<<4096, 256, 0, stream>>>(xbf, wxT, b, xproj, nullptr, nullptr, nullptr, 32);

    // zero initial h slots + flags (xbf dead now; hseq0 aliases it)
    hipMemsetAsync(hseq0, 0, 65536, stream);
    hipMemsetAsync(hseq1, 0, 65536, stream);
    hipMemsetAsync(flagA, 0, 1024, stream);   // flagA + flagB

    // decoupled 2-layer recurrence
    k_fused<<<128, 256, 0, stream>>>(whT, wxT + 4194304, whT + 4194304, xproj,
                                     b + 4096, hseq0, hseq1, flagA, flagB);

    // unpack hseq1 -> plain rows, then heads
    k_unpack<<<8192, 256, 0, stream>>>(hseq1, h1lin);
    k_gemm<1><<<512, 256, 0, stream>>>(h1lin, whdT, bmu, nullptr, out, bls, ym, 4);
}

// Round 15
// 6669.832 us; speedup vs baseline: 2.2897x; 1.5701x over previous
//
#include <hip/hip_runtime.h>

typedef unsigned short u16;
typedef unsigned int   u32;
typedef unsigned long long u64;
typedef short s16x4 __attribute__((ext_vector_type(4)));
typedef short s16x8 __attribute__((ext_vector_type(8)));
typedef float f32x4 __attribute__((ext_vector_type(4)));
typedef u32   u32x4 __attribute__((ext_vector_type(4)));

#define GK 1024

__device__ inline u16 f2bf(float f) {
    u32 u = __builtin_bit_cast(u32, f);
    u += 0x7FFFu + ((u >> 16) & 1u);
    return (u16)(u >> 16);
}
__device__ inline u16 f2h(float f) {
    _Float16 h = (_Float16)f;
    return __builtin_bit_cast(u16, h);
}
__device__ inline float h2f(u16 u) {
    return (float)__builtin_bit_cast(_Float16, u);
}
__device__ inline float fast_sigmoid(float x) {
    return __builtin_amdgcn_rcpf(1.f + __expf(-x));
}
__device__ inline float fast_tanh(float x) {
    return 1.f - 2.f * __builtin_amdgcn_rcpf(1.f + __expf(2.f * x));
}
__device__ inline f32x4 mfma16(s16x8 a, s16x8 b, f32x4 c) {
    return __builtin_amdgcn_mfma_f32_16x16x32_bf16(a, b, c, 0, 0, 0);
}
__device__ inline s16x8 mk8(s16x4 lo, s16x4 hi) {
    return __builtin_shufflevector(lo, hi, 0, 1, 2, 3, 4, 5, 6, 7);
}

// ---------------- f32 -> bf16 convert (x) ----------------
__global__ void k_f2bf(const float* __restrict__ in, u16* __restrict__ out, int n) {
    int i = (blockIdx.x * 256 + threadIdx.x) * 4;
    if (i < n) {
        float4 v = *(const float4*)(in + i);
        ushort4 o;
        o.x = f2bf(v.x); o.y = f2bf(v.y); o.z = f2bf(v.z); o.w = f2bf(v.w);
        *(ushort4*)(out + i) = o;
    }
}

// ---------------- transpose + convert: out[c][r] = bf16(in[r][c]) ----------------
__global__ void k_transpose_bf(const float* __restrict__ in, u16* __restrict__ out,
                               int R, int C) {
    __shared__ float tile[32][33];
    int tid = threadIdx.x;
    int xs = (tid & 7) * 4;
    int y  = tid >> 3;
    int r0 = blockIdx.y * 32, c0 = blockIdx.x * 32;
    float4 v = *(const float4*)(in + (size_t)(r0 + y) * C + c0 + xs);
    tile[y][xs + 0] = v.x; tile[y][xs + 1] = v.y;
    tile[y][xs + 2] = v.z; tile[y][xs + 3] = v.w;
    __syncthreads();
    ushort4 o;
    o.x = f2bf(tile[xs + 0][y]); o.y = f2bf(tile[xs + 1][y]);
    o.z = f2bf(tile[xs + 2][y]); o.w = f2bf(tile[xs + 3][y]);
    *(ushort4*)(out + (size_t)(c0 + y) * R + r0 + xs) = o;
}

// ---------------- in-place frag-pack of a [cols][1024] bf16 matrix (r12-proven) ------
// Per 64B chunk (32 elems): out u64 words = [w0,w4,w1,w5,w2,w6,w3,w7] so a dwordx4 at
// +r16*8 elems is the MFMA B-frag (k = r16*4 + (j&3) + 16*(j>>2)).
__global__ void k_wpackip(u16* __restrict__ wm) {
    int idx = blockIdx.x * 256 + threadIdx.x;
    u64* p = (u64*)(wm + (size_t)idx * 32);
    u64 w0 = p[0], w1 = p[1], w2 = p[2], w3 = p[3];
    u64 w4 = p[4], w5 = p[5], w6 = p[6], w7 = p[7];
    p[0] = w0; p[1] = w4; p[2] = w1; p[3] = w5;
    p[4] = w2; p[5] = w6; p[6] = w3; p[7] = w7;
}

// ---------------- unpack permuted hseq1 -> plain [t*32+b][1024] (r12-proven) ----------
__global__ void k_unpack(const u16* __restrict__ in, u16* __restrict__ out) {
    int idx = blockIdx.x * 256 + threadIdx.x;
    int slot = idx >> 12;
    int c = idx & 4095;
    int q = c >> 7, b = (c >> 2) & 31, ri = c & 3;
    const u16* p = in + (size_t)(slot + 1) * 32768 + q * 1024 + b * 32 + ri * 8;
    u64 lo = *(const u64*)p;
    u64 hi = *(const u64*)(p + 4);
    u16* o = out + (size_t)(slot * 32 + b) * 1024 + q * 32 + ri * 4;
    *(u64*)o = lo;
    *(u64*)(o + 16) = hi;
}

// ---------------- bf16 GEMM (A plain [M][1024]) ----------------
// MODE 0: xproj: orow=(m&511)*32+(m>>9), fp16 gate-interleaved.
// MODE 1: heads: orow=(m&31)*512+(m>>5); n<256 softplus+ymin -> mu; n>=256 -> log_sigma.
template<int MODE>
__launch_bounds__(256, 2)
__global__ void k_gemm(const u16* __restrict__ A, const u16* __restrict__ BT,
                       const float* __restrict__ bias,
                       u16* __restrict__ Cb, float* __restrict__ Cf,
                       const float* __restrict__ b2, const float* __restrict__ ymin,
                       int gridN) {
    int bid = blockIdx.x;
    int m0 = (bid / gridN) * 128, n0 = (bid % gridN) * 128;
    __shared__ u16 As[128 * 40];
    __shared__ u16 Bs[128 * 40];
    int tid = threadIdx.x;
    int lane = tid & 63, w = tid >> 6;
    int wr = w >> 1, wc = w & 1;
    int rr = lane & 15, r16 = lane >> 4;
    f32x4 acc[4][4] = {};
    for (int kt = 0; kt < GK / 32; ++kt) {
        int k0 = kt * 32;
#pragma unroll
        for (int it = 0; it < 2; ++it) {
            int idx = it * 256 + tid;
            int row = idx >> 2, ch = idx & 3;
            *(u32x4*)(&As[row * 40 + ch * 8]) =
                *(const u32x4*)(A + (size_t)(m0 + row) * GK + k0 + ch * 8);
            *(u32x4*)(&Bs[row * 40 + ch * 8]) =
                *(const u32x4*)(BT + (size_t)(n0 + row) * GK + k0 + ch * 8);
        }
        __syncthreads();
        s16x8 af[4], bfr[4];
#pragma unroll
        for (int i = 0; i < 4; ++i) {
            int abase = (wr * 64 + i * 16 + rr) * 40 + r16 * 4;
            af[i] = mk8(*(const s16x4*)(&As[abase]), *(const s16x4*)(&As[abase + 16]));
            int bbase = (wc * 64 + i * 16 + rr) * 40 + r16 * 4;
            bfr[i] = mk8(*(const s16x4*)(&Bs[bbase]), *(const s16x4*)(&Bs[bbase + 16]));
        }
#pragma unroll
        for (int i = 0; i < 4; ++i)
#pragma unroll
            for (int j = 0; j < 4; ++j)
                acc[i][j] = mfma16(af[i], bfr[j], acc[i][j]);
        __syncthreads();
    }
#pragma unroll
    for (int i = 0; i < 4; ++i) {
#pragma unroll
        for (int j = 0; j < 4; ++j) {
#pragma unroll
            for (int r = 0; r < 4; ++r) {
                int m = m0 + wr * 64 + i * 16 + r16 * 4 + r;
                int n = n0 + wc * 64 + j * 16 + rr;
                float v = acc[i][j][r];
                if (MODE == 0) {
                    v += bias[n];
                    int orow = (m & 511) * 32 + (m >> 9);
                    int colx = ((n & 1023) << 2) | (n >> 10);
                    Cb[(size_t)orow * 4096 + colx] = f2h(v);
                } else {
                    int orow = (m & 31) * 512 + (m >> 5);
                    if (n < 256) {
                        v += bias[n];
                        float sp = fmaxf(v, 0.f) + log1pf(expf(-fabsf(v)));
                        Cf[(size_t)orow * 256 + n] = sp + ymin[n];
                    } else {
                        v += b2[n - 256];
                        Cf[4194304 + (size_t)orow * 256 + (n - 256)] = v;
                    }
                }
            }
        }
    }
}

// ---------------- LSTM helpers (r11/r12/r14-proven) ----------------
__device__ inline float lstm_core(f32x4 acc, float ai, float af, float ag, float ao,
                                  float& c, int lane) {
    float r0 = acc[0], r1 = acc[1], r2 = acc[2], r3 = acc[3];
    float x0 = __shfl_xor(r0, 1), x1 = __shfl_xor(r1, 1);
    float x2 = __shfl_xor(r2, 1), x3 = __shfl_xor(r3, 1);
    bool o1 = lane & 1;
    float s0 = o1 ? x1 : r0, s1 = o1 ? r1 : x0;
    float s2 = o1 ? x3 : r2, s3 = o1 ? r3 : x2;
    float y0 = __shfl_xor(s0, 2), y1 = __shfl_xor(s1, 2);
    float y2 = __shfl_xor(s2, 2), y3 = __shfl_xor(s3, 2);
    bool o2 = lane & 2;
    float gi = (o2 ? y2 : s0) + ai;
    float gf = (o2 ? y3 : s1) + af;
    float gg = (o2 ? s2 : y0) + ag;
    float go = (o2 ? s3 : y1) + ao;
    float I  = fast_sigmoid(gi);
    float Fg = fast_sigmoid(gf);
    float G  = fast_tanh(gg);
    float O  = fast_sigmoid(go);
    c = Fg * c + I * G;
    return O * fast_tanh(c);
}
__device__ inline void pack_plain(float h, int lane, u16* dst) {
    u32 hq = (u32)f2bf(h);
    u32 o4 = (u32)__shfl_xor((int)hq, 4);
    u32 m32 = (lane & 4) ? ((o4 & 0xffffu) | (hq << 16))
                         : ((hq & 0xffffu) | (o4 << 16));
    u32 o8 = (u32)__shfl_xor((int)m32, 8);
    u64 m64 = (lane & 8) ? (((u64)o8) | ((u64)m32 << 32))
                         : (((u64)m32) | ((u64)o8 << 32));
    if ((lane & 12) == 0) *(u64*)dst = m64;
}
__device__ inline int e0_of(int base) {
    return ((base & 15) >> 2) * 8 + ((base >> 4) & 1) * 4;
}

// ---------------- per-timestep kernel: boundary IS the sync ----------------
// 256 blocks x 256 threads (4 waves: mt=w&1 batch-half, qh=w>>1 K-half).
// blocks 0-127: L0 step t  (h0[t] in hbuf0 slot t&1 -> slot (t+1)&1), skip at t=512.
// blocks 128-255: L1 step t (h1[t-1] + h0[t]*Wx1 -> hseq1 slot t), skip at t=0.
// All loads/stores PLAIN (dependent-dispatch coherence). Weights frag-packed (k_wpackip):
// one 16B load per B-frag. c-state in f32 global, in-place per (b,unit) thread.
__launch_bounds__(256, 1)
__global__ void k_step(int t,
                       const u16* __restrict__ Wp0, const u16* __restrict__ Wpx,
                       const u16* __restrict__ Wp1, const u16* __restrict__ xproj,
                       const float* __restrict__ b1,
                       u16* __restrict__ hbuf0, u16* __restrict__ hseq1,
                       float* __restrict__ c0buf, float* __restrict__ c1buf) {
    __shared__ f32x4 part[2][2][2][64];   // [mt][ct][src H/X][lane]
    int tid = threadIdx.x, bid = blockIdx.x;
    int lane = tid & 63, w = tid >> 6;
    int mt = w & 1, qh = w >> 1;
    int rr = lane & 15, r16 = lane >> 4;
    int b_ = mt * 16 + ((lane >> 4) << 2) + (lane & 3);
    int uu = (lane >> 2) & 3;
    const int cb = mt * 512 + rr * 32 + r16 * 8;

    if (bid < 128) {
        if (t >= 512) return;
        int blk = bid;
        size_t cg0 = (size_t)((rr & 3) * 1024 + blk * 8 + (rr >> 2));
        const u16* w0 = Wp0 + cg0 * GK + qh * 512 + r16 * 8;
        const u16* w1 = Wp0 + (cg0 + 4) * GK + qh * 512 + r16 * 8;
        const u16* hp = hbuf0 + (size_t)(t & 1) * 32768 + qh * 16384 + cb;
        u32x4 hf[16];
#pragma unroll
        for (int j = 0; j < 16; ++j) hf[j] = *(const u32x4*)(hp + j * 1024);
        f32x4 a0 = {}, a1 = {};
#pragma unroll
        for (int j = 0; j < 16; ++j) {
            s16x8 a = __builtin_bit_cast(s16x8, hf[j]);
            a0 = mfma16(a, *(const s16x8*)(w0 + j * 32), a0);
            a1 = mfma16(a, *(const s16x8*)(w1 + j * 32), a1);
        }
        part[mt][1 - qh][0][lane] = qh ? a0 : a1;
        __syncthreads();
        f32x4 acc = (qh ? a1 : a0) + part[mt][qh][0][lane];
        int unit = blk * 8 + qh * 4 + uu;
        u64 xv = *(const u64*)(xproj + (size_t)(t * 32 + b_) * 4096 + unit * 4);
        float c = c0buf[b_ * 1024 + unit];
        float h = lstm_core(acc, h2f((u16)xv), h2f((u16)(xv >> 16)),
                            h2f((u16)(xv >> 32)), h2f((u16)(xv >> 48)), c, lane);
        c0buf[b_ * 1024 + unit] = c;
        int E0 = e0_of((blk & 3) * 8 + qh * 4);
        u16* dst = hbuf0 + (size_t)((t + 1) & 1) * 32768 + (blk >> 2) * 1024
                 + b_ * 32 + E0;
        pack_plain(h, lane, dst);
    } else {
        if (t < 1) return;
        int blk = bid - 128;
        size_t cg0 = (size_t)((rr & 3) * 1024 + blk * 8 + (rr >> 2));
        size_t woff = qh * 512 + r16 * 8;
        const u16* wh0 = Wp1 + cg0 * GK + woff;
        const u16* wh1 = Wp1 + (cg0 + 4) * GK + woff;
        const u16* wx0 = Wpx + cg0 * GK + woff;
        const u16* wx1 = Wpx + (cg0 + 4) * GK + woff;
        const u16* hp1 = hseq1 + (size_t)(t - 1) * 32768 + qh * 16384 + cb;
        const u16* hp0 = hbuf0 + (size_t)(t & 1) * 32768 + qh * 16384 + cb;
        u32x4 hf[16], gfr[16];
#pragma unroll
        for (int j = 0; j < 16; ++j) hf[j] = *(const u32x4*)(hp1 + j * 1024);
#pragma unroll
        for (int j = 0; j < 16; ++j) gfr[j] = *(const u32x4*)(hp0 + j * 1024);
        f32x4 aH0 = {}, aH1 = {}, aX0 = {}, aX1 = {};
#pragma unroll
        for (int j = 0; j < 16; ++j) {
            s16x8 a = __builtin_bit_cast(s16x8, hf[j]);
            aH0 = mfma16(a, *(const s16x8*)(wh0 + j * 32), aH0);
            aH1 = mfma16(a, *(const s16x8*)(wh1 + j * 32), aH1);
            s16x8 g = __builtin_bit_cast(s16x8, gfr[j]);
            aX0 = mfma16(g, *(const s16x8*)(wx0 + j * 32), aX0);
            aX1 = mfma16(g, *(const s16x8*)(wx1 + j * 32), aX1);
        }
        part[mt][1 - qh][0][lane] = qh ? aH0 : aH1;
        part[mt][1 - qh][1][lane] = qh ? aX0 : aX1;
        __syncthreads();
        f32x4 acc = (qh ? aH1 : aH0) + (qh ? aX1 : aX0)
                  + part[mt][qh][0][lane] + part[mt][qh][1][lane];
        int unit = blk * 8 + qh * 4 + uu;
        float c = c1buf[b_ * 1024 + unit];
        float h = lstm_core(acc, b1[unit], b1[1024 + unit], b1[2048 + unit],
                            b1[3072 + unit], c, lane);
        c1buf[b_ * 1024 + unit] = c;
        int E0 = e0_of((blk & 3) * 8 + qh * 4);
        u16* dst = hseq1 + (size_t)t * 32768 + (blk >> 2) * 1024 + b_ * 32 + E0;
        pack_plain(h, lane, dst);
    }
}

extern "C" void kernel_launch(void* const* d_in, const int* in_sizes, int n_in,
                              void* d_out, int out_size, void* d_ws, size_t ws_size,
                              hipStream_t stream) {
    const float* x   = (const float*)d_in[0];
    const float* Wx  = (const float*)d_in[1];
    const float* Wh  = (const float*)d_in[2];
    const float* b   = (const float*)d_in[3];
    const float* Wmu = (const float*)d_in[4];
    const float* bmu = (const float*)d_in[5];
    const float* Wls = (const float*)d_in[6];
    const float* bls = (const float*)d_in[7];
    const float* ym  = (const float*)d_in[8];
    float* out = (float*)d_out;

    // workspace (235,995,136 B total):
    // [0)            xbf (prep) -> then hbuf0[2][32768] (131,072) + c0 (131,072) + c1
    // [33,554,432)   wxT   16,777,216   [2][4096][1024]  (layer1 half frag-packed)
    // [50,331,648)   whT   16,777,216   (frag-packed in place)
    // [67,108,864)   whdT   1,048,576
    // [68,157,440)   xproj 134,217,728  fp16 gate-interleaved (h1lin alias after steps)
    // [202,375,168)  hseq1 33,619,968   [513][32768]
    char* ws = (char*)d_ws;
    u16*   xbf   = (u16*)(ws);
    u16*   hbuf0 = (u16*)(ws);                   // aliases xbf (dead after gemm0)
    float* c0buf = (float*)(ws + 131072);
    float* c1buf = (float*)(ws + 262144);
    u16*   wxT   = (u16*)(ws + 33554432);
    u16*   whT   = (u16*)(ws + 50331648);
    u16*   whdT  = (u16*)(ws + 67108864);
    u16*   xproj = (u16*)(ws + 68157440);
    u16*   h1lin = xproj;                        // xproj dead after steps
    u16*   hseq1 = (u16*)(ws + 202375168);

    // prep
    k_f2bf<<<16384, 256, 0, stream>>>(x, xbf, 16777216);
    dim3 tg(128, 32);
    k_transpose_bf<<<tg, 256, 0, stream>>>(Wx,           wxT,           1024, 4096);
    k_transpose_bf<<<tg, 256, 0, stream>>>(Wx + 4194304, wxT + 4194304, 1024, 4096);
    k_transpose_bf<<<tg, 256, 0, stream>>>(Wh,           whT,           1024, 4096);
    k_transpose_bf<<<tg, 256, 0, stream>>>(Wh + 4194304, whT + 4194304, 1024, 4096);
    dim3 hg(8, 32);
    k_transpose_bf<<<hg, 256, 0, stream>>>(Wmu, whdT,          1024, 256);
    k_transpose_bf<<<hg, 256, 0, stream>>>(Wls, whdT + 262144, 1024, 256);

    // layer-0 x-projection (reads xbf with UNPACKED wxT[0])
    k_gemm<0><<<4096, 256, 0, stream>>>(xbf, wxT, b, xproj, nullptr, nullptr, nullptr, 32);

    // frag-pack recurrence weights in place (whT both layers, wxT layer 1)
    k_wpackip<<<1024, 256, 0, stream>>>(whT);
    k_wpackip<<<512, 256, 0, stream>>>(wxT + 4194304);

    // init state (xbf dead now): h0 slot0, h1 slot0, c0, c1 = 0
    hipMemsetAsync(hbuf0, 0, 65536, stream);
    hipMemsetAsync(c0buf, 0, 262144, stream);      // c0 + c1
    hipMemsetAsync(hseq1, 0, 65536, stream);

    // 513 per-step kernels; dependent-dispatch boundary = global sync
    for (int t = 0; t <= 512; ++t)
        k_step<<<256, 256, 0, stream>>>(t, whT, wxT + 4194304, whT + 4194304, xproj,
                                        b + 4096, hbuf0, hseq1, c0buf, c1buf);

    // unpack hseq1 -> plain rows, then heads
    k_unpack<<<8192, 256, 0, stream>>>(hseq1, h1lin);
    k_gemm<1><<<512, 256, 0, stream>>>(h1lin, whdT, bmu, nullptr, out, bls, ym, 4);
}